// Round 1
// baseline (243.148 us; speedup 1.0000x reference)
//
#include <hip/hip_runtime.h>
#include <hip/hip_bf16.h>

#define BB 64
#define PP 576
#define DD 1024
#define HH 512

typedef __attribute__((ext_vector_type(4))) float f32x4;
typedef __attribute__((ext_vector_type(8))) short bf16x8;

__device__ __forceinline__ unsigned short f2bf(float f) {
    union { float f; unsigned u; } v; v.f = f;
    unsigned r = v.u + 0x7FFF + ((v.u >> 16) & 1);
    return (unsigned short)(r >> 16);
}

__device__ __forceinline__ float fast_tanh(float x) {
    float e = __expf(2.f * x);
    return 1.f - 2.f / (e + 1.f);
}

// ---- kernel 0: convert W_img fp32 -> bf16 in ws ----
__global__ __launch_bounds__(256) void k_convert(const float* __restrict__ w,
                                                 unsigned short* __restrict__ o) {
    int i = (blockIdx.x * 256 + threadIdx.x) * 4;
    f32x4 v = *(const f32x4*)(w + i);
    ushort4 r;
    r.x = f2bf(v.x); r.y = f2bf(v.y); r.z = f2bf(v.z); r.w = f2bf(v.w);
    *(ushort4*)(o + i) = r;
}

// ---- kernel 1: g[b][h] = tanh(seq[b]·W_seq[h]) * W_w[h]  (fp32 exact path) ----
__global__ __launch_bounds__(512) void k_seq(const float* __restrict__ seq,
                                             const float* __restrict__ W_seq,
                                             const float* __restrict__ W_w,
                                             float* __restrict__ g) {
    int b = blockIdx.x;
    int h = threadIdx.x;  // 512
    __shared__ float s_seq[DD];
    s_seq[h] = seq[b * DD + h];
    s_seq[h + 512] = seq[b * DD + h + 512];
    __syncthreads();
    const float* wr = W_seq + (size_t)h * DD;
    float acc = 0.f;
    #pragma unroll 4
    for (int d = 0; d < DD; d += 4) {
        f32x4 w4 = *(const f32x4*)(wr + d);
        acc += w4.x * s_seq[d] + w4.y * s_seq[d + 1] + w4.z * s_seq[d + 2] + w4.w * s_seq[d + 3];
    }
    g[b * HH + h] = fast_tanh(acc) * W_w[h];
}

// ---- kernel 2: scores[b][p] = sum_h tanh(img[b,p,:]·W_img[h,:]) * g[b,h] ----
// bf16 MFMA 16x16x32. Block: 256 thr = 4 waves, tile BM=64 rows x N=512 cols, BK=32.
#define BM 64
#define BK 32
#define LDK 40  // padded LDS row (bf16 elems): 80B stride -> no serious bank conflicts

__global__ __launch_bounds__(256) void k_scores(const float* __restrict__ img,
                                                const unsigned short* __restrict__ Wb,
                                                const float* __restrict__ g,
                                                float* __restrict__ scores) {
    int b = blockIdx.y;
    int rt = blockIdx.x;  // 0..8
    int p0 = rt * BM;
    int tid = threadIdx.x;
    int wave = tid >> 6, lane = tid & 63;

    __shared__ unsigned short As[BM * LDK];   // 5 KB
    __shared__ unsigned short Bs[HH * LDK];   // 40 KB
    __shared__ float gs[HH];

    gs[tid] = g[b * HH + tid];
    gs[tid + 256] = g[b * HH + tid + 256];

    f32x4 acc[32];
    #pragma unroll
    for (int i = 0; i < 32; i++) acc[i] = (f32x4)0.f;

    const float* arow_base = img + ((size_t)b * PP + p0) * DD;

    for (int k0 = 0; k0 < DD; k0 += BK) {
        // stage A: 64 rows x 32 f32 -> bf16. thread t: row=t>>2, kq=(t&3)*8
        {
            int row = tid >> 2, kq = (tid & 3) * 8;
            const float* src = arow_base + (size_t)row * DD + k0 + kq;
            f32x4 v0 = *(const f32x4*)src;
            f32x4 v1 = *(const f32x4*)(src + 4);
            bf16x8 pk;
            pk[0] = (short)f2bf(v0.x); pk[1] = (short)f2bf(v0.y);
            pk[2] = (short)f2bf(v0.z); pk[3] = (short)f2bf(v0.w);
            pk[4] = (short)f2bf(v1.x); pk[5] = (short)f2bf(v1.y);
            pk[6] = (short)f2bf(v1.z); pk[7] = (short)f2bf(v1.w);
            *(bf16x8*)&As[row * LDK + kq] = pk;
        }
        // stage B: 512 rows x 32 bf16 = 2048 chunks of 8 bf16; 8 chunks/thread
        #pragma unroll
        for (int i = 0; i < 8; i++) {
            int c = tid + i * 256;
            int hrow = c >> 2, kq = (c & 3) * 8;
            bf16x8 v = *(const bf16x8*)(Wb + (size_t)hrow * DD + k0 + kq);
            *(bf16x8*)&Bs[hrow * LDK + kq] = v;
        }
        __syncthreads();

        int rA = wave * 16 + (lane & 15);
        int kA = (lane >> 4) * 8;
        bf16x8 a = *(const bf16x8*)&As[rA * LDK + kA];
        #pragma unroll
        for (int ct = 0; ct < 32; ct++) {
            bf16x8 bfrag = *(const bf16x8*)&Bs[(ct * 16 + (lane & 15)) * LDK + kA];
            acc[ct] = __builtin_amdgcn_mfma_f32_16x16x32_bf16(a, bfrag, acc[ct], 0, 0, 0);
        }
        __syncthreads();
    }

    // epilogue: tanh * g, reduce over the 512 cols
    float partial[4] = {0.f, 0.f, 0.f, 0.f};
    #pragma unroll
    for (int ct = 0; ct < 32; ct++) {
        float gv = gs[ct * 16 + (lane & 15)];
        f32x4 v = acc[ct];
        #pragma unroll
        for (int j = 0; j < 4; j++) partial[j] += fast_tanh(v[j]) * gv;
    }
    #pragma unroll
    for (int m = 1; m < 16; m <<= 1) {
        #pragma unroll
        for (int j = 0; j < 4; j++) partial[j] += __shfl_xor(partial[j], m, 64);
    }
    if ((lane & 15) == 0) {
        int rowg = lane >> 4;
        #pragma unroll
        for (int j = 0; j < 4; j++) {
            int p = p0 + wave * 16 + rowg * 4 + j;
            scores[b * PP + p] = partial[j];
        }
    }
}

// ---- kernel 3: softmax over P per batch ----
__global__ __launch_bounds__(576) void k_softmax(const float* __restrict__ scores,
                                                 float* __restrict__ alpha) {
    int b = blockIdx.x;
    int t = threadIdx.x;  // 0..575
    __shared__ float red[9];
    float s = scores[b * PP + t];
    float m = s;
    #pragma unroll
    for (int off = 32; off; off >>= 1) m = fmaxf(m, __shfl_xor(m, off, 64));
    int w = t >> 6;
    if ((t & 63) == 0) red[w] = m;
    __syncthreads();
    float gm = red[0];
    #pragma unroll
    for (int i = 1; i < 9; i++) gm = fmaxf(gm, red[i]);
    float e = __expf(s - gm);
    float sum = e;
    #pragma unroll
    for (int off = 32; off; off >>= 1) sum += __shfl_xor(sum, off, 64);
    __syncthreads();
    if ((t & 63) == 0) red[w] = sum;
    __syncthreads();
    float gsum = 0.f;
    #pragma unroll
    for (int i = 0; i < 9; i++) gsum += red[i];
    alpha[b * PP + t] = e / gsum;
}

// ---- kernel 4: partial weighted sums over 64-patch chunks ----
__global__ __launch_bounds__(256) void k_attend(const float* __restrict__ img,
                                                const float* __restrict__ alpha,
                                                float* __restrict__ part) {
    int b = blockIdx.y;
    int pc = blockIdx.x;  // 0..8
    int t = threadIdx.x;
    __shared__ float al[64];
    if (t < 64) al[t] = alpha[b * PP + pc * 64 + t];
    __syncthreads();
    int d = t * 4;
    f32x4 acc = (f32x4)0.f;
    const float* base = img + ((size_t)b * PP + (size_t)pc * 64) * DD + d;
    #pragma unroll 4
    for (int i = 0; i < 64; i++) {
        f32x4 v = *(const f32x4*)(base + (size_t)i * DD);
        acc += al[i] * v;
    }
    float* o = part + ((size_t)pc * BB + b) * DD + d;
    *(f32x4*)o = acc;
}

// ---- kernel 5: reduce the 9 partials ----
__global__ __launch_bounds__(256) void k_reduce(const float* __restrict__ part,
                                                float* __restrict__ out) {
    int i = blockIdx.x * 256 + threadIdx.x;  // 0..65535
    float s = 0.f;
    #pragma unroll
    for (int pc = 0; pc < 9; pc++) s += part[pc * (BB * DD) + i];
    out[i] = s;
}

extern "C" void kernel_launch(void* const* d_in, const int* in_sizes, int n_in,
                              void* d_out, int out_size, void* d_ws, size_t ws_size,
                              hipStream_t stream) {
    const float* seq   = (const float*)d_in[0];   // [64,1024]
    const float* img   = (const float*)d_in[1];   // [64,576,1024]
    const float* W_seq = (const float*)d_in[2];   // [512,1024]
    const float* W_img = (const float*)d_in[3];   // [512,1024]
    const float* W_w   = (const float*)d_in[4];   // [1,512]
    float* out = (float*)d_out;                   // [64,1024]

    char* ws = (char*)d_ws;
    unsigned short* Wb = (unsigned short*)ws;                       // 1 MB
    float* g      = (float*)(ws + (1 << 20));                       // 128 KB
    float* scores = (float*)(ws + (1 << 20) + 131072);              // 144 KB
    float* alpha  = (float*)(ws + (1 << 20) + 131072 + 147456);     // 144 KB
    float* part   = (float*)(ws + (1 << 20) + 131072 + 2 * 147456); // 2.25 MB

    k_convert<<<512, 256, 0, stream>>>(W_img, Wb);
    k_seq<<<BB, 512, 0, stream>>>(seq, W_seq, W_w, g);
    k_scores<<<dim3(9, BB), 256, 0, stream>>>(img, Wb, g, scores);
    k_softmax<<<BB, 576, 0, stream>>>(scores, alpha);
    k_attend<<<dim3(9, BB), 256, 0, stream>>>(img, alpha, part);
    k_reduce<<<256, 256, 0, stream>>>(part, out);
}

// Round 2
// 124.303 us; speedup vs baseline: 1.9561x; 1.9561x over previous
//
#include <hip/hip_runtime.h>
#include <hip/hip_bf16.h>

#define BB 64
#define PP 576
#define DD 1024
#define HH 512

typedef __attribute__((ext_vector_type(4))) float f32x4;
typedef __attribute__((ext_vector_type(8))) short bf16x8;

__device__ __forceinline__ unsigned short f2bf(float f) {
    union { float f; unsigned u; } v; v.f = f;
    unsigned r = v.u + 0x7FFF + ((v.u >> 16) & 1);
    return (unsigned short)(r >> 16);
}

__device__ __forceinline__ float fast_tanh(float x) {
    float e = __expf(2.f * x);
    return 1.f - 2.f / (e + 1.f);
}

__device__ __forceinline__ void gload16(const void* g, void* l) {
    __builtin_amdgcn_global_load_lds((const __attribute__((address_space(1))) unsigned int*)g,
                                     (__attribute__((address_space(3))) unsigned int*)l,
                                     16, 0, 0);
}

// ---- kernel 0: convert W_img fp32 -> bf16 in ws ----
__global__ __launch_bounds__(256) void k_convert(const float* __restrict__ w,
                                                 unsigned short* __restrict__ o) {
    int i = (blockIdx.x * 256 + threadIdx.x) * 4;
    f32x4 v = *(const f32x4*)(w + i);
    ushort4 r;
    r.x = f2bf(v.x); r.y = f2bf(v.y); r.z = f2bf(v.z); r.w = f2bf(v.w);
    *(ushort4*)(o + i) = r;
}

// ---- kernel 1: g[b][h] = tanh(seq[b]·W_seq[h]) * W_w[h]  (fp32 exact path) ----
__global__ __launch_bounds__(128) void k_seq(const float* __restrict__ seq,
                                             const float* __restrict__ W_seq,
                                             const float* __restrict__ W_w,
                                             float* __restrict__ g) {
    int b = blockIdx.x;
    int h = blockIdx.y * 128 + threadIdx.x;
    __shared__ float s_seq[DD];
    #pragma unroll
    for (int i = 0; i < 8; i++) s_seq[threadIdx.x + i * 128] = seq[b * DD + threadIdx.x + i * 128];
    __syncthreads();
    const float* wr = W_seq + (size_t)h * DD;
    float acc = 0.f;
    #pragma unroll 4
    for (int d = 0; d < DD; d += 4) {
        f32x4 w4 = *(const f32x4*)(wr + d);
        acc += w4.x * s_seq[d] + w4.y * s_seq[d + 1] + w4.z * s_seq[d + 2] + w4.w * s_seq[d + 3];
    }
    g[b * HH + h] = fast_tanh(acc) * W_w[h];
}

// ---- kernel 2: partial scores via bf16 MFMA, register-blocked 4x4 per wave ----
// Block: 256 thr = 4 waves. Tile: BM=64 rows x HC=256 cols, BK=64 per staging round.
// Wave w handles cols [w*64, w*64+64). Grid (9*2, 64): x%9=row-tile, x/9=col-half.
// LDS layout: rows of 64 bf16 (128B), 16B-chunk XOR-swizzled: chunk_sw = chunk ^ (row&7).
__global__ __launch_bounds__(256) void k_scores(const float* __restrict__ img,
                                                const unsigned short* __restrict__ Wb,
                                                const float* __restrict__ g,
                                                float* __restrict__ sp) {
    int b = blockIdx.y;
    int rt = blockIdx.x % 9;
    int ch = blockIdx.x / 9;
    int p0 = rt * 64;
    int h0 = ch * 256;
    int tid = threadIdx.x;
    int w = tid >> 6, lane = tid & 63;

    __shared__ unsigned short As[64 * 64];    // 8 KB
    __shared__ unsigned short Bs[256 * 64];   // 32 KB
    __shared__ float gs[256];
    __shared__ float red[4][64];

    gs[tid] = g[b * HH + h0 + tid];

    f32x4 acc[4][4];
    #pragma unroll
    for (int m = 0; m < 4; m++)
        #pragma unroll
        for (int n = 0; n < 4; n++) acc[m][n] = (f32x4)0.f;

    // A staging geometry: thread t handles row t>>2, cols (t&3)*16 .. +15
    int ar = tid >> 2;
    int ac = (tid & 3) * 16;
    const float* asrc = img + ((size_t)(b * PP + p0 + ar)) * DD + ac;
    int cp = (tid & 3) * 2;
    int aw0 = ar * 64 + ((cp ^ (ar & 7)) * 8);
    int aw1 = ar * 64 + (((cp + 1) ^ (ar & 7)) * 8);

    // B staging geometry (global_load_lds, pre-swizzled source)
    int brow_l = lane >> 3;   // 0..7 within 8-row segment
    int bchunk = lane & 7;    // 16B chunk within 128B row

    for (int kr = 0; kr < 16; ++kr) {
        int k0 = kr * 64;
        if (kr) __syncthreads();
        // B: 8 wave-issues x 1024B, linear LDS dest, swizzled global source
        #pragma unroll
        for (int i = 0; i < 8; ++i) {
            int hr = (w * 8 + i) * 8 + brow_l;
            const unsigned short* src = Wb + (size_t)(h0 + hr) * DD + k0 + ((bchunk ^ (hr & 7)) * 8);
            gload16(src, &Bs[(w * 8 + i) * 512]);
        }
        // A: reg-stage 16 f32 -> 2 swizzled bf16x8 writes
        f32x4 v0 = *(const f32x4*)(asrc + k0);
        f32x4 v1 = *(const f32x4*)(asrc + k0 + 4);
        f32x4 v2 = *(const f32x4*)(asrc + k0 + 8);
        f32x4 v3 = *(const f32x4*)(asrc + k0 + 12);
        bf16x8 pa, pb;
        pa[0] = (short)f2bf(v0.x); pa[1] = (short)f2bf(v0.y);
        pa[2] = (short)f2bf(v0.z); pa[3] = (short)f2bf(v0.w);
        pa[4] = (short)f2bf(v1.x); pa[5] = (short)f2bf(v1.y);
        pa[6] = (short)f2bf(v1.z); pa[7] = (short)f2bf(v1.w);
        pb[0] = (short)f2bf(v2.x); pb[1] = (short)f2bf(v2.y);
        pb[2] = (short)f2bf(v2.z); pb[3] = (short)f2bf(v2.w);
        pb[4] = (short)f2bf(v3.x); pb[5] = (short)f2bf(v3.y);
        pb[6] = (short)f2bf(v3.z); pb[7] = (short)f2bf(v3.w);
        *(bf16x8*)&As[aw0] = pa;
        *(bf16x8*)&As[aw1] = pb;
        __syncthreads();   // drains vmcnt (global_load_lds) + lgkm (ds_write)

        #pragma unroll
        for (int ks = 0; ks < 2; ++ks) {
            int cbase = ks * 4 + (lane >> 4);   // 16B chunk index 0..7
            bf16x8 af[4], bfv[4];
            #pragma unroll
            for (int m = 0; m < 4; ++m) {
                int row = m * 16 + (lane & 15);
                af[m] = *(const bf16x8*)&As[row * 64 + ((cbase ^ (row & 7)) * 8)];
            }
            #pragma unroll
            for (int n = 0; n < 4; ++n) {
                int hr = w * 64 + n * 16 + (lane & 15);
                bfv[n] = *(const bf16x8*)&Bs[hr * 64 + ((cbase ^ (hr & 7)) * 8)];
            }
            #pragma unroll
            for (int m = 0; m < 4; ++m)
                #pragma unroll
                for (int n = 0; n < 4; ++n)
                    acc[m][n] = __builtin_amdgcn_mfma_f32_16x16x32_bf16(af[m], bfv[n], acc[m][n], 0, 0, 0);
        }
    }

    // epilogue: tanh * g, reduce over this block's 256 cols
    float part[4][4];
    #pragma unroll
    for (int m = 0; m < 4; m++)
        #pragma unroll
        for (int j = 0; j < 4; j++) part[m][j] = 0.f;
    #pragma unroll
    for (int m = 0; m < 4; ++m)
        #pragma unroll
        for (int n = 0; n < 4; ++n) {
            float gv = gs[w * 64 + n * 16 + (lane & 15)];
            f32x4 v = acc[m][n];
            #pragma unroll
            for (int j = 0; j < 4; ++j) part[m][j] += fast_tanh(v[j]) * gv;
        }
    #pragma unroll
    for (int mask = 1; mask < 16; mask <<= 1)
        #pragma unroll
        for (int m = 0; m < 4; ++m)
            #pragma unroll
            for (int j = 0; j < 4; ++j)
                part[m][j] += __shfl_xor(part[m][j], mask, 64);
    if ((lane & 15) == 0) {
        int hi = lane >> 4;
        #pragma unroll
        for (int m = 0; m < 4; ++m)
            #pragma unroll
            for (int j = 0; j < 4; ++j)
                red[w][m * 16 + hi * 4 + j] = part[m][j];
    }
    __syncthreads();
    if (tid < 64) {
        float s = red[0][tid] + red[1][tid] + red[2][tid] + red[3][tid];
        sp[(size_t)ch * (BB * PP) + b * PP + p0 + tid] = s;
    }
}

// ---- kernel 3: sum the 2 col-half partials + softmax over P per batch ----
__global__ __launch_bounds__(576) void k_softmax(const float* __restrict__ sp,
                                                 float* __restrict__ alpha) {
    int b = blockIdx.x;
    int t = threadIdx.x;  // 0..575
    __shared__ float red[9];
    float s = sp[b * PP + t] + sp[BB * PP + b * PP + t];
    float m = s;
    #pragma unroll
    for (int off = 32; off; off >>= 1) m = fmaxf(m, __shfl_xor(m, off, 64));
    int w = t >> 6;
    if ((t & 63) == 0) red[w] = m;
    __syncthreads();
    float gm = red[0];
    #pragma unroll
    for (int i = 1; i < 9; i++) gm = fmaxf(gm, red[i]);
    float e = __expf(s - gm);
    float sum = e;
    #pragma unroll
    for (int off = 32; off; off >>= 1) sum += __shfl_xor(sum, off, 64);
    __syncthreads();
    if ((t & 63) == 0) red[w] = sum;
    __syncthreads();
    float gsum = 0.f;
    #pragma unroll
    for (int i = 0; i < 9; i++) gsum += red[i];
    alpha[b * PP + t] = e / gsum;
}

// ---- kernel 4: partial weighted sums over 64-patch chunks ----
__global__ __launch_bounds__(256) void k_attend(const float* __restrict__ img,
                                                const float* __restrict__ alpha,
                                                float* __restrict__ part) {
    int b = blockIdx.y;
    int pc = blockIdx.x;  // 0..8
    int t = threadIdx.x;
    __shared__ float al[64];
    if (t < 64) al[t] = alpha[b * PP + pc * 64 + t];
    __syncthreads();
    int d = t * 4;
    f32x4 acc = (f32x4)0.f;
    const float* base = img + ((size_t)b * PP + (size_t)pc * 64) * DD + d;
    #pragma unroll 4
    for (int i = 0; i < 64; i++) {
        f32x4 v = *(const f32x4*)(base + (size_t)i * DD);
        acc += al[i] * v;
    }
    float* o = part + ((size_t)pc * BB + b) * DD + d;
    *(f32x4*)o = acc;
}

// ---- kernel 5: reduce the 9 partials ----
__global__ __launch_bounds__(256) void k_reduce(const float* __restrict__ part,
                                                float* __restrict__ out) {
    int i = blockIdx.x * 256 + threadIdx.x;  // 0..65535
    float s = 0.f;
    #pragma unroll
    for (int pc = 0; pc < 9; pc++) s += part[pc * (BB * DD) + i];
    out[i] = s;
}

extern "C" void kernel_launch(void* const* d_in, const int* in_sizes, int n_in,
                              void* d_out, int out_size, void* d_ws, size_t ws_size,
                              hipStream_t stream) {
    const float* seq   = (const float*)d_in[0];   // [64,1024]
    const float* img   = (const float*)d_in[1];   // [64,576,1024]
    const float* W_seq = (const float*)d_in[2];   // [512,1024]
    const float* W_img = (const float*)d_in[3];   // [512,1024]
    const float* W_w   = (const float*)d_in[4];   // [1,512]
    float* out = (float*)d_out;                   // [64,1024]

    char* ws = (char*)d_ws;
    unsigned short* Wb = (unsigned short*)ws;                        // 1 MB
    float* g      = (float*)(ws + 1048576);                          // 128 KB
    float* sp     = (float*)(ws + 1048576 + 131072);                 // 2*144 KB (partial scores)
    float* alpha  = (float*)(ws + 1048576 + 131072 + 294912);        // 144 KB
    float* part   = (float*)(ws + 1048576 + 131072 + 294912 + 147456); // 2.25 MB

    k_convert<<<512, 256, 0, stream>>>(W_img, Wb);
    k_seq<<<dim3(BB, 4), 128, 0, stream>>>(seq, W_seq, W_w, g);
    k_scores<<<dim3(18, BB), 256, 0, stream>>>(img, Wb, g, sp);
    k_softmax<<<BB, 576, 0, stream>>>(sp, alpha);
    k_attend<<<dim3(9, BB), 256, 0, stream>>>(img, alpha, part);
    k_reduce<<<256, 256, 0, stream>>>(part, out);
}